// Round 1
// baseline (975.564 us; speedup 1.0000x reference)
//
#include <hip/hip_runtime.h>
#include <hip/hip_bf16.h>
#include <stdint.h>

#define INPUT_DIM 1024
#define PRED_LEN 96
#define HIDDEN 512
#define BATCH 4096
#define W1_ROWS 1032  // INPUT_DIM + DAY_EMB

typedef __attribute__((ext_vector_type(8))) short bf16x8;
typedef __attribute__((ext_vector_type(4))) float floatx4;

__device__ __forceinline__ unsigned short f32_to_bf16_rne(float f) {
    union { float f; unsigned int u; } v; v.f = f;
    unsigned int u = v.u;
    unsigned int r = u + 0x7fffu + ((u >> 16) & 1u);
    return (unsigned short)(r >> 16);
}

__device__ __forceinline__ void async_copy16(const void* g, void* l) {
    __builtin_amdgcn_global_load_lds(
        (const __attribute__((address_space(1))) unsigned int*)g,
        (__attribute__((address_space(3))) unsigned int*)l, 16, 0, 0);
}

// ---------------------------------------------------------------- convert x
__global__ void convert_x_kernel(const float* __restrict__ x,
                                 unsigned short* __restrict__ xb) {
    int i = (blockIdx.x * 256 + threadIdx.x) * 4;
    float4 v = *reinterpret_cast<const float4*>(x + i);
    ushort4 o;
    o.x = f32_to_bf16_rne(v.x);
    o.y = f32_to_bf16_rne(v.y);
    o.z = f32_to_bf16_rne(v.z);
    o.w = f32_to_bf16_rne(v.w);
    *reinterpret_cast<ushort4*>(xb + i) = o;
}

// ------------------------------------------- transpose+convert W1x -> (p,n,k)
// Round-5 4x4 register-block transpose (harness-verified). Unchanged.
__global__ void transpose_w1_kernel(const float* __restrict__ W1,
                                    unsigned short* __restrict__ W1t) {
    __shared__ unsigned short tile[64 * 64];  // [n][k], swizzled chunks
    int bid = blockIdx.x;
    int nt = bid & 7;          // n tile (8 x 64)
    int kt = (bid >> 3) & 15;  // k tile (16 x 64)
    int p  = bid >> 7;
    int t  = threadIdx.x;
    const float* src = W1 + (size_t)p * W1_ROWS * HIDDEN;
    const int k0 = kt * 64, n0 = nt * 64;

    const int tn = t & 15;    // n-group
    const int tk = t >> 4;    // k-group 0..15
    float4 v[4];
    #pragma unroll
    for (int i = 0; i < 4; ++i)
        v[i] = *reinterpret_cast<const float4*>(src + (size_t)(k0 + 4 * tk + i) * HIDDEN + n0 + 4 * tn);
    const int slot1 = ((tk >> 2) ^ (tn & 3)) * 16 + (tk & 3) * 4;
    {
        ushort4 w0, w1, w2, w3;
        w0.x = f32_to_bf16_rne(v[0].x); w0.y = f32_to_bf16_rne(v[1].x);
        w0.z = f32_to_bf16_rne(v[2].x); w0.w = f32_to_bf16_rne(v[3].x);
        w1.x = f32_to_bf16_rne(v[0].y); w1.y = f32_to_bf16_rne(v[1].y);
        w1.z = f32_to_bf16_rne(v[2].y); w1.w = f32_to_bf16_rne(v[3].y);
        w2.x = f32_to_bf16_rne(v[0].z); w2.y = f32_to_bf16_rne(v[1].z);
        w2.z = f32_to_bf16_rne(v[2].z); w2.w = f32_to_bf16_rne(v[3].z);
        w3.x = f32_to_bf16_rne(v[0].w); w3.y = f32_to_bf16_rne(v[1].w);
        w3.z = f32_to_bf16_rne(v[2].w); w3.w = f32_to_bf16_rne(v[3].w);
        *reinterpret_cast<ushort4*>(tile + (4 * tn + 0) * 64 + slot1) = w0;
        *reinterpret_cast<ushort4*>(tile + (4 * tn + 1) * 64 + slot1) = w1;
        *reinterpret_cast<ushort4*>(tile + (4 * tn + 2) * 64 + slot1) = w2;
        *reinterpret_cast<ushort4*>(tile + (4 * tn + 3) * 64 + slot1) = w3;
    }
    __syncthreads();

    const int nr = t >> 2;
    const int q  = t & 3;
    const int slot2 = (q ^ ((nr >> 2) & 3)) * 16;
    uint4 a = *reinterpret_cast<const uint4*>(tile + nr * 64 + slot2);
    uint4 b = *reinterpret_cast<const uint4*>(tile + nr * 64 + slot2 + 8);
    size_t dst = ((size_t)p * HIDDEN + n0 + nr) * 1024 + k0 + q * 16;
    *reinterpret_cast<uint4*>(W1t + dst)     = a;
    *reinterpret_cast<uint4*>(W1t + dst + 8) = b;
}

// -------------------------------------------------- exact f32 bias precompute
__global__ void bias_kernel(const float* __restrict__ W1,
                            const float* __restrict__ day_emb,
                            const float* __restrict__ b1,
                            float* __restrict__ bias) {
    int p = blockIdx.x;
    int h = threadIdx.x;  // 512 threads
    const float* W1e = W1 + ((size_t)p * W1_ROWS + INPUT_DIM) * HIDDEN;
    float acc = b1[p * HIDDEN + h];
    #pragma unroll
    for (int e = 0; e < 8; ++e)
        acc += day_emb[p * 8 + e] * W1e[(size_t)e * HIDDEN + h];
    bias[p * HIDDEN + h] = acc;
}

// ------------------------------------- fused GEMM + relu + W2 reduction + b2
// Round-6: T3 minimal 2-phase pipeline. BK 64->32, double-buffered LDS
// (same 32 KB footprint as the old single-buffered BK=64 pair -> occupancy
// unchanged). Per K-step: ISSUE next tile's global_load_lds into buf^1 FIRST,
// then ds_read+16 MFMA from buf, then ONE __syncthreads() (its implicit
// vmcnt(0) drain now lands ~200+ cycles after issue -> staging latency hides
// under compute instead of serializing; old structure drained vmcnt before
// any MFMA, costing ~48% of cycles at MfmaUtil 51.7%).
// Swizzle re-derived for 4 chunks/row: LDS slot s of row r holds global
// k-chunk s^(r&3); pre-applied on the GLOBAL address (gload_lds dest must be
// linear lane*16). Read slot = quad^(l15&3) -> 2-way bank aliasing (free).
__global__ void __launch_bounds__(256, 3)
mlp_head_kernel(const unsigned short* __restrict__ xb,   // 4096x1024 bf16
                const unsigned short* __restrict__ W1t,  // 96x512x1024 bf16 (N-major)
                const float* __restrict__ bias,          // 96x512 f32
                const float* __restrict__ W2,            // 96x512 f32
                const float* __restrict__ b2,            // 96 f32
                float* __restrict__ out)                 // 4096x96 f32
{
    __shared__ unsigned short As[2][128 * 32];  // [buf][row][32k], chunk-swizzled
    __shared__ unsigned short Bs[2][128 * 32];
    __shared__ float w2s[HIDDEN];
    __shared__ float biass[HIDDEN];
    __shared__ float red[2][128];

    const int mt   = blockIdx.x;  // 0..31 batch tile
    const int p    = blockIdx.y;  // 0..95
    const int t    = threadIdx.x;
    const int lane = t & 63;
    const int w    = t >> 6;
    const int wi   = w >> 1;      // row half (64)
    const int wj   = w & 1;       // col half (64)
    const int l15  = lane & 15;
    const int quad = lane >> 4;
    const int slt  = quad ^ (l15 & 3);   // read chunk slot (16B units)

    // staging: thread t owns LDS chunk t (rows 0..63) and chunk t+256 (rows
    // 64..127), both at linear lane*16 dest; global src pre-swizzled.
    const int r0   = t >> 2;                       // staging row 0..63
    const int skc  = (((t & 3) ^ (r0 & 3))) * 8;   // swizzled k-offset (shorts)
    const int ldso = t * 8;                        // LDS dest offset (shorts)

    for (int i = t; i < HIDDEN; i += 256) {
        w2s[i]   = W2[p * HIDDEN + i];
        biass[i] = bias[p * HIDDEN + i];
    }

    const int m0 = mt * 128;
    const unsigned short* ag = xb  + (size_t)(m0 + r0) * 1024 + skc;
    const unsigned short* bg = W1t + ((size_t)p * HIDDEN + r0) * 1024 + skc;

    float partial[4][4];
    #pragma unroll
    for (int i = 0; i < 4; ++i)
        #pragma unroll
        for (int r = 0; r < 4; ++r) partial[i][r] = 0.f;

    for (int nt = 0; nt < 4; ++nt) {
        floatx4 acc[4][4];
        #pragma unroll
        for (int i = 0; i < 4; ++i)
            #pragma unroll
            for (int j = 0; j < 4; ++j)
                acc[i][j] = (floatx4){0.f, 0.f, 0.f, 0.f};

        const size_t bn = (size_t)nt * 128 * 1024;  // n-tile offset in W1t

        // prologue: stage K-step 0 into buf 0 (syncthreads drains vmcnt)
        async_copy16(ag,                 As[0] + ldso);
        async_copy16(ag + 64 * 1024,     As[0] + 2048 + ldso);
        async_copy16(bg + bn,            Bs[0] + ldso);
        async_copy16(bg + bn + 64 * 1024, Bs[0] + 2048 + ldso);
        __syncthreads();

        #pragma unroll 2
        for (int ks = 0; ks < 32; ++ks) {
            const int cur = ks & 1;
            // issue-early: prefetch next K-step into the other buffer
            if (ks < 31) {
                const int k0 = (ks + 1) * 32;
                async_copy16(ag + k0,                  As[cur ^ 1] + ldso);
                async_copy16(ag + 64 * 1024 + k0,      As[cur ^ 1] + 2048 + ldso);
                async_copy16(bg + bn + k0,             Bs[cur ^ 1] + ldso);
                async_copy16(bg + bn + 64 * 1024 + k0, Bs[cur ^ 1] + 2048 + ldso);
            }
            // compute current buffer: 8 ds_read_b128 + 16 MFMA
            bf16x8 af[4], bfr[4];
            #pragma unroll
            for (int i = 0; i < 4; ++i) {
                int r = wi * 64 + i * 16 + l15;
                af[i] = *reinterpret_cast<const bf16x8*>(As[cur] + r * 32 + slt * 8);
            }
            #pragma unroll
            for (int j = 0; j < 4; ++j) {
                int n = wj * 64 + j * 16 + l15;
                bfr[j] = *reinterpret_cast<const bf16x8*>(Bs[cur] + n * 32 + slt * 8);
            }
            #pragma unroll
            for (int i = 0; i < 4; ++i)
                #pragma unroll
                for (int j = 0; j < 4; ++j)
                    acc[i][j] = __builtin_amdgcn_mfma_f32_16x16x32_bf16(
                        af[i], bfr[j], acc[i][j], 0, 0, 0);
            // drain-late: loads issued above have had ~full compute phase
            __syncthreads();
        }

        // epilogue for this n-tile: bias + relu + weight by W2, fold into partials
        const int n0 = nt * 128;
        #pragma unroll
        for (int j = 0; j < 4; ++j) {
            int c = n0 + wj * 64 + j * 16 + l15;  // C layout: col = lane&15
            float w2v = w2s[c];
            float bv  = biass[c];
            #pragma unroll
            for (int i = 0; i < 4; ++i)
                #pragma unroll
                for (int r = 0; r < 4; ++r) {
                    float hv = acc[i][j][r] + bv;
                    hv = hv > 0.f ? hv : 0.f;
                    partial[i][r] += hv * w2v;
                }
        }
    }

    // reduce over columns: 16 lanes of each quad hold distinct cols of same rows
    #pragma unroll
    for (int i = 0; i < 4; ++i)
        #pragma unroll
        for (int r = 0; r < 4; ++r) {
            float v = partial[i][r];
            v += __shfl_xor(v, 1);
            v += __shfl_xor(v, 2);
            v += __shfl_xor(v, 4);
            v += __shfl_xor(v, 8);
            partial[i][r] = v;
        }

    if (l15 == 0) {
        #pragma unroll
        for (int i = 0; i < 4; ++i)
            #pragma unroll
            for (int r = 0; r < 4; ++r) {
                int row = wi * 64 + i * 16 + quad * 4 + r;  // C layout: row = quad*4+reg
                red[wj][row] = partial[i][r];
            }
    }
    __syncthreads();
    if (t < 128) {
        float v = red[0][t] + red[1][t] + b2[p];
        out[(size_t)(m0 + t) * PRED_LEN + p] = v;
    }
}

// ---------------------------------------------------------------------------
extern "C" void kernel_launch(void* const* d_in, const int* in_sizes, int n_in,
                              void* d_out, int out_size, void* d_ws, size_t ws_size,
                              hipStream_t stream) {
    const float* x       = (const float*)d_in[0];
    const float* day_emb = (const float*)d_in[1];
    const float* W1      = (const float*)d_in[2];
    const float* b1      = (const float*)d_in[3];
    const float* W2      = (const float*)d_in[4];
    const float* b2      = (const float*)d_in[5];
    float* out = (float*)d_out;

    const size_t xb_bytes  = (size_t)BATCH * INPUT_DIM * 2;             // 8,388,608
    const size_t w1t_bytes = (size_t)PRED_LEN * HIDDEN * INPUT_DIM * 2; // 100,663,296
    const size_t bias_bytes = (size_t)PRED_LEN * HIDDEN * 4;            // 196,608
    if (ws_size < xb_bytes + w1t_bytes + bias_bytes) return;

    unsigned short* xb  = (unsigned short*)d_ws;
    unsigned short* w1t = (unsigned short*)((char*)d_ws + xb_bytes);
    float* biasp        = (float*)((char*)d_ws + xb_bytes + w1t_bytes);

    convert_x_kernel<<<(BATCH * INPUT_DIM) / (256 * 4), 256, 0, stream>>>(x, xb);
    transpose_w1_kernel<<<PRED_LEN * 16 * 8, 256, 0, stream>>>(W1, w1t);
    bias_kernel<<<PRED_LEN, HIDDEN, 0, stream>>>(W1, day_emb, b1, biasp);

    dim3 grid(BATCH / 128, PRED_LEN);
    mlp_head_kernel<<<grid, 256, 0, stream>>>(xb, w1t, biasp, W2, b2, out);
}

// Round 2
// 676.397 us; speedup vs baseline: 1.4423x; 1.4423x over previous
//
#include <hip/hip_runtime.h>
#include <hip/hip_bf16.h>
#include <stdint.h>

#define INPUT_DIM 1024
#define PRED_LEN 96
#define HIDDEN 512
#define BATCH 4096
#define W1_ROWS 1032  // INPUT_DIM + DAY_EMB

typedef __attribute__((ext_vector_type(8))) short bf16x8;
typedef __attribute__((ext_vector_type(4))) float floatx4;

__device__ __forceinline__ unsigned short f32_to_bf16_rne(float f) {
    union { float f; unsigned int u; } v; v.f = f;
    unsigned int u = v.u;
    unsigned int r = u + 0x7fffu + ((u >> 16) & 1u);
    return (unsigned short)(r >> 16);
}

__device__ __forceinline__ void async_copy16(const void* g, void* l) {
    __builtin_amdgcn_global_load_lds(
        (const __attribute__((address_space(1))) unsigned int*)g,
        (__attribute__((address_space(3))) unsigned int*)l, 16, 0, 0);
}

// ---------------------------------------------------------------- convert x
__global__ void convert_x_kernel(const float* __restrict__ x,
                                 unsigned short* __restrict__ xb) {
    int i = (blockIdx.x * 256 + threadIdx.x) * 4;
    float4 v = *reinterpret_cast<const float4*>(x + i);
    ushort4 o;
    o.x = f32_to_bf16_rne(v.x);
    o.y = f32_to_bf16_rne(v.y);
    o.z = f32_to_bf16_rne(v.z);
    o.w = f32_to_bf16_rne(v.w);
    *reinterpret_cast<ushort4*>(xb + i) = o;
}

// ------------------------------------------- transpose+convert W1x -> (p,n,k)
// Round-5 4x4 register-block transpose (harness-verified). Unchanged.
__global__ void transpose_w1_kernel(const float* __restrict__ W1,
                                    unsigned short* __restrict__ W1t) {
    __shared__ unsigned short tile[64 * 64];  // [n][k], swizzled chunks
    int bid = blockIdx.x;
    int nt = bid & 7;          // n tile (8 x 64)
    int kt = (bid >> 3) & 15;  // k tile (16 x 64)
    int p  = bid >> 7;
    int t  = threadIdx.x;
    const float* src = W1 + (size_t)p * W1_ROWS * HIDDEN;
    const int k0 = kt * 64, n0 = nt * 64;

    const int tn = t & 15;    // n-group
    const int tk = t >> 4;    // k-group 0..15
    float4 v[4];
    #pragma unroll
    for (int i = 0; i < 4; ++i)
        v[i] = *reinterpret_cast<const float4*>(src + (size_t)(k0 + 4 * tk + i) * HIDDEN + n0 + 4 * tn);
    const int slot1 = ((tk >> 2) ^ (tn & 3)) * 16 + (tk & 3) * 4;
    {
        ushort4 w0, w1, w2, w3;
        w0.x = f32_to_bf16_rne(v[0].x); w0.y = f32_to_bf16_rne(v[1].x);
        w0.z = f32_to_bf16_rne(v[2].x); w0.w = f32_to_bf16_rne(v[3].x);
        w1.x = f32_to_bf16_rne(v[0].y); w1.y = f32_to_bf16_rne(v[1].y);
        w1.z = f32_to_bf16_rne(v[2].y); w1.w = f32_to_bf16_rne(v[3].y);
        w2.x = f32_to_bf16_rne(v[0].z); w2.y = f32_to_bf16_rne(v[1].z);
        w2.z = f32_to_bf16_rne(v[2].z); w2.w = f32_to_bf16_rne(v[3].z);
        w3.x = f32_to_bf16_rne(v[0].w); w3.y = f32_to_bf16_rne(v[1].w);
        w3.z = f32_to_bf16_rne(v[2].w); w3.w = f32_to_bf16_rne(v[3].w);
        *reinterpret_cast<ushort4*>(tile + (4 * tn + 0) * 64 + slot1) = w0;
        *reinterpret_cast<ushort4*>(tile + (4 * tn + 1) * 64 + slot1) = w1;
        *reinterpret_cast<ushort4*>(tile + (4 * tn + 2) * 64 + slot1) = w2;
        *reinterpret_cast<ushort4*>(tile + (4 * tn + 3) * 64 + slot1) = w3;
    }
    __syncthreads();

    const int nr = t >> 2;
    const int q  = t & 3;
    const int slot2 = (q ^ ((nr >> 2) & 3)) * 16;
    uint4 a = *reinterpret_cast<const uint4*>(tile + nr * 64 + slot2);
    uint4 b = *reinterpret_cast<const uint4*>(tile + nr * 64 + slot2 + 8);
    size_t dst = ((size_t)p * HIDDEN + n0 + nr) * 1024 + k0 + q * 16;
    *reinterpret_cast<uint4*>(W1t + dst)     = a;
    *reinterpret_cast<uint4*>(W1t + dst + 8) = b;
}

// -------------------------------------------------- exact f32 bias precompute
__global__ void bias_kernel(const float* __restrict__ W1,
                            const float* __restrict__ day_emb,
                            const float* __restrict__ b1,
                            float* __restrict__ bias) {
    int p = blockIdx.x;
    int h = threadIdx.x;  // 512 threads
    const float* W1e = W1 + ((size_t)p * W1_ROWS + INPUT_DIM) * HIDDEN;
    float acc = b1[p * HIDDEN + h];
    #pragma unroll
    for (int e = 0; e < 8; ++e)
        acc += day_emb[p * 8 + e] * W1e[(size_t)e * HIDDEN + h];
    bias[p * HIDDEN + h] = acc;
}

// ------------------------------------- fused GEMM + relu + W2 reduction + b2
// Round-7: 256^2 8-phase template port (guide m201). 8 waves (2M x 4N),
// per-wave 128x64, acc[8][4], BK=64, double-buffered 128 KB LDS.
// Per K-tile: 4 phases, each {ds_read subtile; (stage 4 gloads ph1-2);
// raw s_barrier; setprio(1); 16 MFMA; setprio(0); raw s_barrier}.
// Next tile's 8 global_load_lds issued phases 1-2, single vmcnt(0) at end of
// phase 4 (>=2 MFMA phases of cover). Raw barriers keep loads in flight
// (round-0/1's __syncthreads drained vmcnt at every barrier = the stall).
// LDS layout: the round-0 MEASURED-zero-conflict swizzle — 64-short (128 B)
// rows, global-side chunk-XOR (t&7)^(row&7), linear lane*16 LDS dest,
// reads at slot=(kk*4+quad)^(l15&7). Full 128 B/row/K-tile staging (round-1's
// 64 B half-line staging doubled FETCH_SIZE — reverted).
__global__ void __launch_bounds__(512, 2)
mlp_head_kernel(const unsigned short* __restrict__ xb,   // 4096x1024 bf16
                const unsigned short* __restrict__ W1t,  // 96x512x1024 bf16 (N-major)
                const float* __restrict__ bias,          // 96x512 f32
                const float* __restrict__ W2,            // 96x512 f32
                const float* __restrict__ b2,            // 96 f32
                float* __restrict__ out)                 // 4096x96 f32
{
    __shared__ unsigned short A_lds[2][256 * 64];  // 64 KB
    __shared__ unsigned short B_lds[2][256 * 64];  // 64 KB
    __shared__ float w2s[HIDDEN];
    __shared__ float biass[HIDDEN];
    __shared__ float red[4][256];

    const int mt   = blockIdx.x;   // 0..15 batch tile (256 rows)
    const int p    = blockIdx.y;   // 0..95
    const int t    = threadIdx.x;  // 0..511
    const int lane = t & 63;
    const int w    = t >> 6;       // 0..7
    const int wm   = w >> 2;       // 0..1  (M half: 128 rows)
    const int wn   = w & 3;        // 0..3  (N quarter: 64 cols)
    const int l15  = lane & 15;
    const int quad = lane >> 4;
    const int sl0  = (quad ^ (l15 & 7)) * 8;        // kk=0 chunk slot (shorts)
    const int sl1  = ((4 + quad) ^ (l15 & 7)) * 8;  // kk=1

    const int aro = (wm * 128 + l15) * 64;  // A frag row base (shorts)
    const int bro = (wn * 64  + l15) * 64;  // B frag row base

    // staging: thread t -> tile row tr=t>>3 (+part*64), chunk t&7 at linear
    // lane*16 LDS dest; global src pre-swizzled by (t&7)^(tr&7).
    const int tr   = t >> 3;                      // 0..63
    const int skc  = ((t & 7) ^ (tr & 7)) * 8;    // swizzled k-chunk (shorts)
    const int ldst = t * 8;                       // LDS dest (shorts)

    const int m0 = mt * 256;
    const unsigned short* agb = xb  + (size_t)(m0 + tr) * 1024 + skc;
    const unsigned short* bgb = W1t + ((size_t)p * HIDDEN + tr) * 1024 + skc;

    for (int i = t; i < HIDDEN; i += 512) {
        w2s[i]   = W2[p * HIDDEN + i];
        biass[i] = bias[p * HIDDEN + i];
    }
    __syncthreads();

    float partial[8][4];
    #pragma unroll
    for (int i = 0; i < 8; ++i)
        #pragma unroll
        for (int r = 0; r < 4; ++r) partial[i][r] = 0.f;

    for (int nt = 0; nt < 2; ++nt) {
        const size_t bnt = (size_t)nt * 256 * 1024;  // n-tile offset in W1t

        floatx4 acc[8][4];
        #pragma unroll
        for (int i = 0; i < 8; ++i)
            #pragma unroll
            for (int j = 0; j < 4; ++j)
                acc[i][j] = (floatx4){0.f, 0.f, 0.f, 0.f};

        // ---- prologue: stage K-tile 0 into buf 0, full drain
        #pragma unroll
        for (int part = 0; part < 4; ++part) {
            async_copy16(agb + (size_t)part * 65536,       &A_lds[0][part * 4096 + ldst]);
            async_copy16(bgb + bnt + (size_t)part * 65536, &B_lds[0][part * 4096 + ldst]);
        }
        asm volatile("s_waitcnt vmcnt(0)" ::: "memory");
        __builtin_amdgcn_s_barrier();

        for (int kt = 0; kt < 16; ++kt) {
            const int cur = kt & 1;
            const unsigned short* Ab = A_lds[cur];
            const unsigned short* Bb = B_lds[cur];
            unsigned short* An = A_lds[cur ^ 1];
            unsigned short* Bn = B_lds[cur ^ 1];
            const int kof = (kt + 1) * 64;  // next tile k offset (shorts)
            bf16x8 af[4][2], bf[2][2];

            // ================= phase 1: i0-3 x j0-1 ====================
            #pragma unroll
            for (int i = 0; i < 4; ++i) {
                af[i][0] = *reinterpret_cast<const bf16x8*>(Ab + aro + i * 1024 + sl0);
                af[i][1] = *reinterpret_cast<const bf16x8*>(Ab + aro + i * 1024 + sl1);
            }
            #pragma unroll
            for (int j = 0; j < 2; ++j) {
                bf[j][0] = *reinterpret_cast<const bf16x8*>(Bb + bro + j * 1024 + sl0);
                bf[j][1] = *reinterpret_cast<const bf16x8*>(Bb + bro + j * 1024 + sl1);
            }
            if (kt < 15) {  // stage next tile parts 0,1 (A+B)
                async_copy16(agb + kof,                &An[ldst]);
                async_copy16(agb + 65536 + kof,        &An[4096 + ldst]);
                async_copy16(bgb + bnt + kof,          &Bn[ldst]);
                async_copy16(bgb + bnt + 65536 + kof,  &Bn[4096 + ldst]);
            }
            __builtin_amdgcn_s_barrier();
            __builtin_amdgcn_s_setprio(1);
            #pragma unroll
            for (int i = 0; i < 4; ++i)
                #pragma unroll
                for (int j = 0; j < 2; ++j) {
                    acc[i][j] = __builtin_amdgcn_mfma_f32_16x16x32_bf16(af[i][0], bf[j][0], acc[i][j], 0, 0, 0);
                    acc[i][j] = __builtin_amdgcn_mfma_f32_16x16x32_bf16(af[i][1], bf[j][1], acc[i][j], 0, 0, 0);
                }
            __builtin_amdgcn_s_setprio(0);
            __builtin_amdgcn_s_barrier();

            // ================= phase 2: i0-3 x j2-3 ====================
            #pragma unroll
            for (int j = 0; j < 2; ++j) {
                bf[j][0] = *reinterpret_cast<const bf16x8*>(Bb + bro + (j + 2) * 1024 + sl0);
                bf[j][1] = *reinterpret_cast<const bf16x8*>(Bb + bro + (j + 2) * 1024 + sl1);
            }
            if (kt < 15) {  // stage next tile parts 2,3 (A+B)
                async_copy16(agb + 131072 + kof,       &An[8192 + ldst]);
                async_copy16(agb + 196608 + kof,       &An[12288 + ldst]);
                async_copy16(bgb + bnt + 131072 + kof, &Bn[8192 + ldst]);
                async_copy16(bgb + bnt + 196608 + kof, &Bn[12288 + ldst]);
            }
            __builtin_amdgcn_s_barrier();
            __builtin_amdgcn_s_setprio(1);
            #pragma unroll
            for (int i = 0; i < 4; ++i)
                #pragma unroll
                for (int j = 0; j < 2; ++j) {
                    acc[i][j + 2] = __builtin_amdgcn_mfma_f32_16x16x32_bf16(af[i][0], bf[j][0], acc[i][j + 2], 0, 0, 0);
                    acc[i][j + 2] = __builtin_amdgcn_mfma_f32_16x16x32_bf16(af[i][1], bf[j][1], acc[i][j + 2], 0, 0, 0);
                }
            __builtin_amdgcn_s_setprio(0);
            __builtin_amdgcn_s_barrier();

            // ================= phase 3: i4-7 x j2-3 ====================
            #pragma unroll
            for (int i = 0; i < 4; ++i) {
                af[i][0] = *reinterpret_cast<const bf16x8*>(Ab + aro + (i + 4) * 1024 + sl0);
                af[i][1] = *reinterpret_cast<const bf16x8*>(Ab + aro + (i + 4) * 1024 + sl1);
            }
            __builtin_amdgcn_s_barrier();
            __builtin_amdgcn_s_setprio(1);
            #pragma unroll
            for (int i = 0; i < 4; ++i)
                #pragma unroll
                for (int j = 0; j < 2; ++j) {
                    acc[i + 4][j + 2] = __builtin_amdgcn_mfma_f32_16x16x32_bf16(af[i][0], bf[j][0], acc[i + 4][j + 2], 0, 0, 0);
                    acc[i + 4][j + 2] = __builtin_amdgcn_mfma_f32_16x16x32_bf16(af[i][1], bf[j][1], acc[i + 4][j + 2], 0, 0, 0);
                }
            __builtin_amdgcn_s_setprio(0);
            __builtin_amdgcn_s_barrier();

            // ================= phase 4: i4-7 x j0-1 ====================
            #pragma unroll
            for (int j = 0; j < 2; ++j) {
                bf[j][0] = *reinterpret_cast<const bf16x8*>(Bb + bro + j * 1024 + sl0);
                bf[j][1] = *reinterpret_cast<const bf16x8*>(Bb + bro + j * 1024 + sl1);
            }
            __builtin_amdgcn_s_barrier();
            __builtin_amdgcn_s_setprio(1);
            #pragma unroll
            for (int i = 0; i < 4; ++i)
                #pragma unroll
                for (int j = 0; j < 2; ++j) {
                    acc[i + 4][j] = __builtin_amdgcn_mfma_f32_16x16x32_bf16(af[i][0], bf[j][0], acc[i + 4][j], 0, 0, 0);
                    acc[i + 4][j] = __builtin_amdgcn_mfma_f32_16x16x32_bf16(af[i][1], bf[j][1], acc[i + 4][j], 0, 0, 0);
                }
            __builtin_amdgcn_s_setprio(0);
            if (kt < 15)
                asm volatile("s_waitcnt vmcnt(0)" ::: "memory");  // next tile landed
            __builtin_amdgcn_s_barrier();
        }

        // epilogue for this n-tile: bias + relu + weight by W2, fold to partial
        const int nb0 = nt * 256;
        #pragma unroll
        for (int j = 0; j < 4; ++j) {
            int c = nb0 + wn * 64 + j * 16 + l15;  // C layout: col = lane&15
            float w2v = w2s[c];
            float bv  = biass[c];
            #pragma unroll
            for (int i = 0; i < 8; ++i)
                #pragma unroll
                for (int r = 0; r < 4; ++r) {
                    float hv = acc[i][j][r] + bv;
                    hv = hv > 0.f ? hv : 0.f;
                    partial[i][r] += hv * w2v;
                }
        }
    }

    // reduce over the 16 columns held by l15 lanes within each quad
    #pragma unroll
    for (int i = 0; i < 8; ++i)
        #pragma unroll
        for (int r = 0; r < 4; ++r) {
            float v = partial[i][r];
            v += __shfl_xor(v, 1);
            v += __shfl_xor(v, 2);
            v += __shfl_xor(v, 4);
            v += __shfl_xor(v, 8);
            partial[i][r] = v;
        }

    if (l15 == 0) {
        #pragma unroll
        for (int i = 0; i < 8; ++i)
            #pragma unroll
            for (int r = 0; r < 4; ++r) {
                int row = wm * 128 + i * 16 + quad * 4 + r;  // C layout: row = quad*4+reg
                red[wn][row] = partial[i][r];
            }
    }
    __syncthreads();
    if (t < 256) {
        float v = red[0][t] + red[1][t] + red[2][t] + red[3][t] + b2[p];
        out[(size_t)(m0 + t) * PRED_LEN + p] = v;
    }
}

// ---------------------------------------------------------------------------
extern "C" void kernel_launch(void* const* d_in, const int* in_sizes, int n_in,
                              void* d_out, int out_size, void* d_ws, size_t ws_size,
                              hipStream_t stream) {
    const float* x       = (const float*)d_in[0];
    const float* day_emb = (const float*)d_in[1];
    const float* W1      = (const float*)d_in[2];
    const float* b1      = (const float*)d_in[3];
    const float* W2      = (const float*)d_in[4];
    const float* b2      = (const float*)d_in[5];
    float* out = (float*)d_out;

    const size_t xb_bytes  = (size_t)BATCH * INPUT_DIM * 2;             // 8,388,608
    const size_t w1t_bytes = (size_t)PRED_LEN * HIDDEN * INPUT_DIM * 2; // 100,663,296
    const size_t bias_bytes = (size_t)PRED_LEN * HIDDEN * 4;            // 196,608
    if (ws_size < xb_bytes + w1t_bytes + bias_bytes) return;

    unsigned short* xb  = (unsigned short*)d_ws;
    unsigned short* w1t = (unsigned short*)((char*)d_ws + xb_bytes);
    float* biasp        = (float*)((char*)d_ws + xb_bytes + w1t_bytes);

    convert_x_kernel<<<(BATCH * INPUT_DIM) / (256 * 4), 256, 0, stream>>>(x, xb);
    transpose_w1_kernel<<<PRED_LEN * 16 * 8, 256, 0, stream>>>(W1, w1t);
    bias_kernel<<<PRED_LEN, HIDDEN, 0, stream>>>(W1, day_emb, b1, biasp);

    dim3 grid(BATCH / 256, PRED_LEN);
    mlp_head_kernel<<<grid, 512, 0, stream>>>(xb, w1t, biasp, W2, b2, out);
}